// Round 1
// baseline (8774.911 us; speedup 1.0000x reference)
//
#include <hip/hip_runtime.h>

#define N_NODES 100000
#define N_EDGES 1600000
#define F 128

// Y[row][col] = sum_k relu?(X[row][k]) * W[k][col]
// block = (128, 2): threadIdx.x = output column, threadIdx.y = local row.
// X row staged in LDS (broadcast reads); W reads are coalesced along col and
// fully L2-resident (64 KB).
__global__ void gemm_relu_in(const float* __restrict__ X, const float* __restrict__ W,
                             float* __restrict__ Y, int relu_in) {
    __shared__ float Xs[2][F];
    const int col = threadIdx.x;
    const int rl  = threadIdx.y;
    const int row = blockIdx.x * 2 + rl;   // grid = N_NODES/2 exactly (no ragged blocks)

    float v = X[(size_t)row * F + col];
    if (relu_in) v = fmaxf(v, 0.0f);
    Xs[rl][col] = v;
    __syncthreads();

    float acc = 0.0f;
#pragma unroll
    for (int k = 0; k < F; ++k) {
        acc += Xs[rl][k] * W[k * F + col];
    }
    Y[(size_t)row * F + col] = acc;
}

// Out[edge_row[e]][:] += edge_weight[e] * X[edge_col[e]][:]
// 32 threads per edge, float4 per thread (128 floats = 32 lanes * 4).
// 8 edges per 256-thread block; grid = N_EDGES/8 exactly.
__global__ void spmm_scatter(const float* __restrict__ X,
                             const int* __restrict__ erow,
                             const int* __restrict__ ecol,
                             const float* __restrict__ ewgt,
                             float* __restrict__ Out) {
    const int e = blockIdx.x * 8 + (threadIdx.x >> 5);
    const int lane = threadIdx.x & 31;

    const int   src = ecol[e];
    const int   dst = erow[e];
    const float w   = ewgt[e];

    const float4 v = ((const float4*)(X + (size_t)src * F))[lane];
    float* o = Out + (size_t)dst * F + lane * 4;
    atomicAdd(o + 0, w * v.x);
    atomicAdd(o + 1, w * v.y);
    atomicAdd(o + 2, w * v.z);
    atomicAdd(o + 3, w * v.w);
}

__global__ void relu_inplace_f4(float4* __restrict__ Y) {
    const int i = blockIdx.x * blockDim.x + threadIdx.x;
    float4 v = Y[i];
    v.x = fmaxf(v.x, 0.0f);
    v.y = fmaxf(v.y, 0.0f);
    v.z = fmaxf(v.z, 0.0f);
    v.w = fmaxf(v.w, 0.0f);
    Y[i] = v;
}

extern "C" void kernel_launch(void* const* d_in, const int* in_sizes, int n_in,
                              void* d_out, int out_size, void* d_ws, size_t ws_size,
                              hipStream_t stream) {
    const float* x    = (const float*)d_in[0];
    const int*   erow = (const int*)d_in[1];
    const int*   ecol = (const int*)d_in[2];
    const float* ew   = (const float*)d_in[3];
    const float* w1   = (const float*)d_in[4];
    const float* w2   = (const float*)d_in[5];
    const float* w3   = (const float*)d_in[6];
    float* out  = (float*)d_out;
    float* buf0 = (float*)d_ws;                      // GEMM output / SpMM input

    const size_t featBytes = (size_t)N_NODES * F * sizeof(float);
    const dim3 gblk(128, 2);
    const int  ggrid = N_NODES / 2;                  // 50000, exact
    const int  sgrid = N_EDGES / 8;                  // 200000, exact

    // Layer 1: buf0 = x @ w1 ; out = A*buf0
    gemm_relu_in<<<ggrid, gblk, 0, stream>>>(x, w1, buf0, 0);
    hipMemsetAsync(out, 0, featBytes, stream);
    spmm_scatter<<<sgrid, 256, 0, stream>>>(buf0, erow, ecol, ew, out);

    // Layer 2: buf0 = relu(out) @ w2 ; out = A*buf0
    gemm_relu_in<<<ggrid, gblk, 0, stream>>>(out, w2, buf0, 1);
    hipMemsetAsync(out, 0, featBytes, stream);
    spmm_scatter<<<sgrid, 256, 0, stream>>>(buf0, erow, ecol, ew, out);

    // Layer 3: buf0 = relu(out) @ w3 ; out = relu(A*buf0)
    gemm_relu_in<<<ggrid, gblk, 0, stream>>>(out, w3, buf0, 1);
    hipMemsetAsync(out, 0, featBytes, stream);
    spmm_scatter<<<sgrid, 256, 0, stream>>>(buf0, erow, ecol, ew, out);
    relu_inplace_f4<<<(N_NODES * F / 4) / 256, 256, 0, stream>>>((float4*)out);
}

// Round 2
// 1427.415 us; speedup vs baseline: 6.1474x; 6.1474x over previous
//
#include <hip/hip_runtime.h>

#define N_NODES 100000
#define N_EDGES 1600000
#define F 128

// ---------------- CSR build ----------------

__global__ void edge_histogram(const int* __restrict__ erow, int* __restrict__ counts) {
    const int e = blockIdx.x * blockDim.x + threadIdx.x;
    atomicAdd(&counts[erow[e]], 1);
}

// Single-block exclusive scan of counts[N_NODES] -> row_ptr[N_NODES+1].
// 1024 threads, each owns a contiguous chunk of 98 rows.
__global__ void scan_counts(const int* __restrict__ counts, int* __restrict__ row_ptr) {
    const int CHUNK = (N_NODES + 1023) / 1024;   // 98
    __shared__ int s[1024];
    const int t = threadIdx.x;
    const int base = t * CHUNK;

    int partial = 0;
    for (int i = 0; i < CHUNK; ++i) {
        int idx = base + i;
        if (idx < N_NODES) partial += counts[idx];
    }
    s[t] = partial;
    __syncthreads();
    // Hillis-Steele inclusive scan over 1024 partials
    for (int off = 1; off < 1024; off <<= 1) {
        int v = (t >= off) ? s[t - off] : 0;
        __syncthreads();
        s[t] += v;
        __syncthreads();
    }
    int run = s[t] - partial;   // exclusive prefix of this chunk
    for (int i = 0; i < CHUNK; ++i) {
        int idx = base + i;
        if (idx < N_NODES) {
            row_ptr[idx] = run;
            run += counts[idx];
        }
    }
    if (t == 0) row_ptr[N_NODES] = N_EDGES;
}

// Scatter edges into CSR buckets. cursor[] must be zeroed first.
__global__ void csr_fill(const int* __restrict__ erow, const int* __restrict__ ecol,
                         const float* __restrict__ ewgt,
                         const int* __restrict__ row_ptr, int* __restrict__ cursor,
                         int* __restrict__ scol, float* __restrict__ sw) {
    const int e = blockIdx.x * blockDim.x + threadIdx.x;
    const int dst = erow[e];
    const int pos = atomicAdd(&cursor[dst], 1);
    const int idx = row_ptr[dst] + pos;
    scol[idx] = ecol[e];
    sw[idx]   = ewgt[e];
}

// ---------------- Dense GEMM (unchanged from R0) ----------------

__global__ void gemm_relu_in(const float* __restrict__ X, const float* __restrict__ W,
                             float* __restrict__ Y, int relu_in) {
    __shared__ float Xs[2][F];
    const int col = threadIdx.x;
    const int rl  = threadIdx.y;
    const int row = blockIdx.x * 2 + rl;

    float v = X[(size_t)row * F + col];
    if (relu_in) v = fmaxf(v, 0.0f);
    Xs[rl][col] = v;
    __syncthreads();

    float acc = 0.0f;
#pragma unroll
    for (int k = 0; k < F; ++k) {
        acc += Xs[rl][k] * W[k * F + col];
    }
    Y[(size_t)row * F + col] = acc;
}

// ---------------- CSR SpMM ----------------
// One wave (64 lanes) per destination row; lane covers 2 columns (float2).
// Edges processed 2 at a time for load ILP. Single non-atomic store per row.
__global__ void spmm_csr(const float* __restrict__ X,
                         const int* __restrict__ row_ptr,
                         const int* __restrict__ scol,
                         const float* __restrict__ sw,
                         float* __restrict__ Out, int relu_out) {
    const int lane = threadIdx.x;                  // 0..63
    const int row  = blockIdx.x * 4 + threadIdx.y; // grid = N_NODES/4 exact

    const int beg = row_ptr[row];
    const int end = row_ptr[row + 1];

    float2 a0 = {0.f, 0.f}, a1 = {0.f, 0.f};
    int i = beg;
    for (; i + 1 < end; i += 2) {
        const int   c0 = scol[i],   c1 = scol[i + 1];
        const float w0 = sw[i],     w1 = sw[i + 1];
        const float2 v0 = ((const float2*)(X + (size_t)c0 * F))[lane];
        const float2 v1 = ((const float2*)(X + (size_t)c1 * F))[lane];
        a0.x += w0 * v0.x; a0.y += w0 * v0.y;
        a1.x += w1 * v1.x; a1.y += w1 * v1.y;
    }
    if (i < end) {
        const int   c0 = scol[i];
        const float w0 = sw[i];
        const float2 v0 = ((const float2*)(X + (size_t)c0 * F))[lane];
        a0.x += w0 * v0.x; a0.y += w0 * v0.y;
    }
    float2 r;
    r.x = a0.x + a1.x;
    r.y = a0.y + a1.y;
    if (relu_out) {
        r.x = fmaxf(r.x, 0.0f);
        r.y = fmaxf(r.y, 0.0f);
    }
    ((float2*)(Out + (size_t)row * F))[lane] = r;
}

// ---------------- launch ----------------

extern "C" void kernel_launch(void* const* d_in, const int* in_sizes, int n_in,
                              void* d_out, int out_size, void* d_ws, size_t ws_size,
                              hipStream_t stream) {
    const float* x    = (const float*)d_in[0];
    const int*   erow = (const int*)d_in[1];
    const int*   ecol = (const int*)d_in[2];
    const float* ew   = (const float*)d_in[3];
    const float* w1   = (const float*)d_in[4];
    const float* w2   = (const float*)d_in[5];
    const float* w3   = (const float*)d_in[6];
    float* out = (float*)d_out;

    // Workspace layout (bump-allocated, 256 B aligned)
    char* ws = (char*)d_ws;
    size_t off = 0;
    auto alloc = [&](size_t bytes) -> char* {
        char* p = ws + off;
        off += (bytes + 255) & ~(size_t)255;
        return p;
    };
    float* buf0    = (float*)alloc((size_t)N_NODES * F * sizeof(float)); // 51.2 MB
    int*   counts  = (int*)  alloc((size_t)N_NODES * sizeof(int));       // 400 KB (doubles as cursor)
    int*   row_ptr = (int*)  alloc(((size_t)N_NODES + 1) * sizeof(int));
    int*   scol    = (int*)  alloc((size_t)N_EDGES * sizeof(int));       // 6.4 MB
    float* swgt    = (float*)alloc((size_t)N_EDGES * sizeof(float));     // 6.4 MB

    // --- CSR build (once; reused by all 3 layers) ---
    hipMemsetAsync(counts, 0, (size_t)N_NODES * sizeof(int), stream);
    edge_histogram<<<N_EDGES / 256, 256, 0, stream>>>(erow, counts);
    scan_counts<<<1, 1024, 0, stream>>>(counts, row_ptr);
    hipMemsetAsync(counts, 0, (size_t)N_NODES * sizeof(int), stream);
    csr_fill<<<N_EDGES / 256, 256, 0, stream>>>(erow, ecol, ew, row_ptr, counts, scol, swgt);

    const dim3 gblk(128, 2);
    const int  ggrid = N_NODES / 2;   // 50000 exact
    const dim3 sblk(64, 4);
    const int  sgrid = N_NODES / 4;   // 25000 exact

    // Layer 1
    gemm_relu_in<<<ggrid, gblk, 0, stream>>>(x, w1, buf0, 0);
    spmm_csr<<<sgrid, sblk, 0, stream>>>(buf0, row_ptr, scol, swgt, out, 0);
    // Layer 2
    gemm_relu_in<<<ggrid, gblk, 0, stream>>>(out, w2, buf0, 1);
    spmm_csr<<<sgrid, sblk, 0, stream>>>(buf0, row_ptr, scol, swgt, out, 0);
    // Layer 3
    gemm_relu_in<<<ggrid, gblk, 0, stream>>>(out, w3, buf0, 1);
    spmm_csr<<<sgrid, sblk, 0, stream>>>(buf0, row_ptr, scol, swgt, out, 1);
}

// Round 3
// 1005.583 us; speedup vs baseline: 8.7262x; 1.4195x over previous
//
#include <hip/hip_runtime.h>

#define N_NODES 100000
#define N_EDGES 1600000
#define F 128

// ---------------- CSR build ----------------

__global__ void edge_histogram(const int* __restrict__ erow, int* __restrict__ counts) {
    const int e = blockIdx.x * blockDim.x + threadIdx.x;
    atomicAdd(&counts[erow[e]], 1);
}

__global__ void scan_counts(const int* __restrict__ counts, int* __restrict__ row_ptr) {
    const int CHUNK = (N_NODES + 1023) / 1024;   // 98
    __shared__ int s[1024];
    const int t = threadIdx.x;
    const int base = t * CHUNK;

    int partial = 0;
    for (int i = 0; i < CHUNK; ++i) {
        int idx = base + i;
        if (idx < N_NODES) partial += counts[idx];
    }
    s[t] = partial;
    __syncthreads();
    for (int off = 1; off < 1024; off <<= 1) {
        int v = (t >= off) ? s[t - off] : 0;
        __syncthreads();
        s[t] += v;
        __syncthreads();
    }
    int run = s[t] - partial;
    for (int i = 0; i < CHUNK; ++i) {
        int idx = base + i;
        if (idx < N_NODES) {
            row_ptr[idx] = run;
            run += counts[idx];
        }
    }
    if (t == 0) row_ptr[N_NODES] = N_EDGES;
}

__global__ void csr_fill(const int* __restrict__ erow, const int* __restrict__ ecol,
                         const float* __restrict__ ewgt,
                         const int* __restrict__ row_ptr, int* __restrict__ cursor,
                         int* __restrict__ scol, float* __restrict__ sw) {
    const int e = blockIdx.x * blockDim.x + threadIdx.x;
    const int dst = erow[e];
    const int pos = atomicAdd(&cursor[dst], 1);
    const int idx = row_ptr[dst] + pos;
    scol[idx] = ecol[e];
    sw[idx]   = ewgt[e];
}

// ---------------- Register-tiled GEMM ----------------
// Block: 256 threads -> 64 rows x 128 cols of Y. Thread (tx=tid%16, ty=tid/16)
// owns a 4x8 micro-tile: rows ty*4..+3, cols tx*8..+7. K tiled by 32.
// LDS: Xs 64x(32+4) pad->float4-aligned stores, bank-shift 4/row; Ws 32x128.
#define BM 64
#define BK 32

__global__ __launch_bounds__(256) void gemm_tiled(const float* __restrict__ X,
                                                  const float* __restrict__ W,
                                                  float* __restrict__ Y, int relu_in) {
    __shared__ float Xs[BM][BK + 4];   // 64*36*4 = 9216 B
    __shared__ float Ws[BK][F];        // 32*128*4 = 16384 B

    const int tid = threadIdx.x;
    const int tx = tid & 15;           // 0..15 -> cols tx*8..tx*8+7
    const int ty = tid >> 4;           // 0..15 -> rows ty*4..ty*4+3
    const int rowBase = blockIdx.x * BM;

    float acc[4][8] = {};

    for (int k0 = 0; k0 < F; k0 += BK) {
        // Stage X tile: 64x32 floats = 512 float4, 2 per thread.
#pragma unroll
        for (int i = 0; i < 2; ++i) {
            const int idx = tid + i * 256;         // 0..511
            const int r = idx >> 3;                // 8 float4 per 32-float row
            const int c = (idx & 7) * 4;
            const int gr = rowBase + r;
            float4 v = {0.f, 0.f, 0.f, 0.f};
            if (gr < N_NODES) v = *(const float4*)(X + (size_t)gr * F + k0 + c);
            if (relu_in) {
                v.x = fmaxf(v.x, 0.f); v.y = fmaxf(v.y, 0.f);
                v.z = fmaxf(v.z, 0.f); v.w = fmaxf(v.w, 0.f);
            }
            *(float4*)(&Xs[r][c]) = v;             // row stride 36 floats -> 16B aligned
        }
        // Stage W panel: 32x128 floats = 1024 float4, 4 per thread.
#pragma unroll
        for (int i = 0; i < 4; ++i) {
            const int idx = tid + i * 256;         // 0..1023
            const int r = idx >> 5;                // 32 float4 per 128-float row
            const int c = (idx & 31) * 4;
            *(float4*)(&Ws[r][c]) = *(const float4*)(W + (size_t)(k0 + r) * F + c);
        }
        __syncthreads();

#pragma unroll
        for (int kk = 0; kk < BK; ++kk) {
            float xv[4], wv[8];
#pragma unroll
            for (int i = 0; i < 4; ++i) xv[i] = Xs[ty * 4 + i][kk];
            *(float4*)&wv[0] = *(float4*)&Ws[kk][tx * 8];
            *(float4*)&wv[4] = *(float4*)&Ws[kk][tx * 8 + 4];
#pragma unroll
            for (int i = 0; i < 4; ++i)
#pragma unroll
                for (int j = 0; j < 8; ++j)
                    acc[i][j] += xv[i] * wv[j];
        }
        __syncthreads();
    }

#pragma unroll
    for (int i = 0; i < 4; ++i) {
        const int gr = rowBase + ty * 4 + i;
        if (gr < N_NODES) {
            float4 o0 = {acc[i][0], acc[i][1], acc[i][2], acc[i][3]};
            float4 o1 = {acc[i][4], acc[i][5], acc[i][6], acc[i][7]};
            *(float4*)(Y + (size_t)gr * F + tx * 8) = o0;
            *(float4*)(Y + (size_t)gr * F + tx * 8 + 4) = o1;
        }
    }
}

// ---------------- CSR SpMM (unchanged from R1) ----------------

__global__ void spmm_csr(const float* __restrict__ X,
                         const int* __restrict__ row_ptr,
                         const int* __restrict__ scol,
                         const float* __restrict__ sw,
                         float* __restrict__ Out, int relu_out) {
    const int lane = threadIdx.x;
    const int row  = blockIdx.x * 4 + threadIdx.y;

    const int beg = row_ptr[row];
    const int end = row_ptr[row + 1];

    float2 a0 = {0.f, 0.f}, a1 = {0.f, 0.f};
    int i = beg;
    for (; i + 1 < end; i += 2) {
        const int   c0 = scol[i],   c1 = scol[i + 1];
        const float w0 = sw[i],     w1 = sw[i + 1];
        const float2 v0 = ((const float2*)(X + (size_t)c0 * F))[lane];
        const float2 v1 = ((const float2*)(X + (size_t)c1 * F))[lane];
        a0.x += w0 * v0.x; a0.y += w0 * v0.y;
        a1.x += w1 * v1.x; a1.y += w1 * v1.y;
    }
    if (i < end) {
        const int   c0 = scol[i];
        const float w0 = sw[i];
        const float2 v0 = ((const float2*)(X + (size_t)c0 * F))[lane];
        a0.x += w0 * v0.x; a0.y += w0 * v0.y;
    }
    float2 r;
    r.x = a0.x + a1.x;
    r.y = a0.y + a1.y;
    if (relu_out) {
        r.x = fmaxf(r.x, 0.0f);
        r.y = fmaxf(r.y, 0.0f);
    }
    ((float2*)(Out + (size_t)row * F))[lane] = r;
}

// ---------------- launch ----------------

extern "C" void kernel_launch(void* const* d_in, const int* in_sizes, int n_in,
                              void* d_out, int out_size, void* d_ws, size_t ws_size,
                              hipStream_t stream) {
    const float* x    = (const float*)d_in[0];
    const int*   erow = (const int*)d_in[1];
    const int*   ecol = (const int*)d_in[2];
    const float* ew   = (const float*)d_in[3];
    const float* w1   = (const float*)d_in[4];
    const float* w2   = (const float*)d_in[5];
    const float* w3   = (const float*)d_in[6];
    float* out = (float*)d_out;

    char* ws = (char*)d_ws;
    size_t off = 0;
    auto alloc = [&](size_t bytes) -> char* {
        char* p = ws + off;
        off += (bytes + 255) & ~(size_t)255;
        return p;
    };
    float* buf0    = (float*)alloc((size_t)N_NODES * F * sizeof(float)); // 51.2 MB
    int*   counts  = (int*)  alloc((size_t)N_NODES * sizeof(int));
    int*   row_ptr = (int*)  alloc(((size_t)N_NODES + 1) * sizeof(int));
    int*   scol    = (int*)  alloc((size_t)N_EDGES * sizeof(int));
    float* swgt    = (float*)alloc((size_t)N_EDGES * sizeof(float));

    // --- CSR build (once; reused by all 3 layers) ---
    hipMemsetAsync(counts, 0, (size_t)N_NODES * sizeof(int), stream);
    edge_histogram<<<N_EDGES / 256, 256, 0, stream>>>(erow, counts);
    scan_counts<<<1, 1024, 0, stream>>>(counts, row_ptr);
    hipMemsetAsync(counts, 0, (size_t)N_NODES * sizeof(int), stream);
    csr_fill<<<N_EDGES / 256, 256, 0, stream>>>(erow, ecol, ew, row_ptr, counts, scol, swgt);

    const int ggrid = (N_NODES + BM - 1) / BM;   // 1563
    const dim3 sblk(64, 4);
    const int  sgrid = N_NODES / 4;              // 25000 exact

    // Layer 1
    gemm_tiled<<<ggrid, 256, 0, stream>>>(x, w1, buf0, 0);
    spmm_csr<<<sgrid, sblk, 0, stream>>>(buf0, row_ptr, scol, swgt, out, 0);
    // Layer 2
    gemm_tiled<<<ggrid, 256, 0, stream>>>(out, w2, buf0, 1);
    spmm_csr<<<sgrid, sblk, 0, stream>>>(buf0, row_ptr, scol, swgt, out, 0);
    // Layer 3
    gemm_tiled<<<ggrid, 256, 0, stream>>>(out, w3, buf0, 1);
    spmm_csr<<<sgrid, sblk, 0, stream>>>(buf0, row_ptr, scol, swgt, out, 1);
}

// Round 4
// 767.525 us; speedup vs baseline: 11.4327x; 1.3102x over previous
//
#include <hip/hip_runtime.h>

#define N_NODES 100000
#define N_EDGES 1600000
#define F 128

#define SCAN_B 1024
#define SCAN_NB ((N_NODES + SCAN_B - 1) / SCAN_B)   // 98

// ---------------- CSR build ----------------

__global__ void edge_histogram(const int* __restrict__ erow, int* __restrict__ counts) {
    const int e = blockIdx.x * blockDim.x + threadIdx.x;
    atomicAdd(&counts[erow[e]], 1);
}

// Phase 1: per-block sums of counts (98 blocks x 1024 threads).
__global__ void scan_block_sums(const int* __restrict__ counts, int* __restrict__ bsums) {
    __shared__ int s[SCAN_B];
    const int t = threadIdx.x;
    const int idx = blockIdx.x * SCAN_B + t;
    int v = (idx < N_NODES) ? counts[idx] : 0;
    s[t] = v;
    __syncthreads();
    for (int off = SCAN_B / 2; off > 0; off >>= 1) {
        if (t < off) s[t] += s[t + off];
        __syncthreads();
    }
    if (t == 0) bsums[blockIdx.x] = s[0];
}

// Phase 2: exclusive-scan the 98 block sums (1 block, 128 threads).
__global__ void scan_bsums(const int* __restrict__ bsums, int* __restrict__ boffs) {
    __shared__ int s[128];
    const int t = threadIdx.x;
    int v = (t < SCAN_NB) ? bsums[t] : 0;
    s[t] = v;
    __syncthreads();
    for (int off = 1; off < 128; off <<= 1) {
        int u = (t >= off) ? s[t - off] : 0;
        __syncthreads();
        s[t] += u;
        __syncthreads();
    }
    if (t < SCAN_NB) boffs[t] = s[t] - v;   // exclusive
}

// Phase 3: per-block exclusive scan + block offset -> row_ptr.
__global__ void scan_final(const int* __restrict__ counts, const int* __restrict__ boffs,
                           int* __restrict__ row_ptr) {
    __shared__ int s[SCAN_B];
    const int t = threadIdx.x;
    const int idx = blockIdx.x * SCAN_B + t;
    int v = (idx < N_NODES) ? counts[idx] : 0;
    s[t] = v;
    __syncthreads();
    for (int off = 1; off < SCAN_B; off <<= 1) {
        int u = (t >= off) ? s[t - off] : 0;
        __syncthreads();
        s[t] += u;
        __syncthreads();
    }
    if (idx < N_NODES) row_ptr[idx] = boffs[blockIdx.x] + s[t] - v;
    if (idx == 0) row_ptr[N_NODES] = N_EDGES;
}

__global__ void csr_fill(const int* __restrict__ erow, const int* __restrict__ ecol,
                         const float* __restrict__ ewgt,
                         const int* __restrict__ row_ptr, int* __restrict__ cursor,
                         int* __restrict__ scol, float* __restrict__ sw) {
    const int e = blockIdx.x * blockDim.x + threadIdx.x;
    const int dst = erow[e];
    const int pos = atomicAdd(&cursor[dst], 1);
    const int idx = row_ptr[dst] + pos;
    scol[idx] = ecol[e];
    sw[idx]   = ewgt[e];
}

// ---------------- Register-tiled GEMM (unchanged from R2) ----------------
#define BM 64
#define BK 32

__global__ __launch_bounds__(256) void gemm_tiled(const float* __restrict__ X,
                                                  const float* __restrict__ W,
                                                  float* __restrict__ Y, int relu_in) {
    __shared__ float Xs[BM][BK + 4];
    __shared__ float Ws[BK][F];

    const int tid = threadIdx.x;
    const int tx = tid & 15;
    const int ty = tid >> 4;
    const int rowBase = blockIdx.x * BM;

    float acc[4][8] = {};

    for (int k0 = 0; k0 < F; k0 += BK) {
#pragma unroll
        for (int i = 0; i < 2; ++i) {
            const int idx = tid + i * 256;
            const int r = idx >> 3;
            const int c = (idx & 7) * 4;
            const int gr = rowBase + r;
            float4 v = {0.f, 0.f, 0.f, 0.f};
            if (gr < N_NODES) v = *(const float4*)(X + (size_t)gr * F + k0 + c);
            if (relu_in) {
                v.x = fmaxf(v.x, 0.f); v.y = fmaxf(v.y, 0.f);
                v.z = fmaxf(v.z, 0.f); v.w = fmaxf(v.w, 0.f);
            }
            *(float4*)(&Xs[r][c]) = v;
        }
#pragma unroll
        for (int i = 0; i < 4; ++i) {
            const int idx = tid + i * 256;
            const int r = idx >> 5;
            const int c = (idx & 31) * 4;
            *(float4*)(&Ws[r][c]) = *(const float4*)(W + (size_t)(k0 + r) * F + c);
        }
        __syncthreads();

#pragma unroll
        for (int kk = 0; kk < BK; ++kk) {
            float xv[4], wv[8];
#pragma unroll
            for (int i = 0; i < 4; ++i) xv[i] = Xs[ty * 4 + i][kk];
            *(float4*)&wv[0] = *(float4*)&Ws[kk][tx * 8];
            *(float4*)&wv[4] = *(float4*)&Ws[kk][tx * 8 + 4];
#pragma unroll
            for (int i = 0; i < 4; ++i)
#pragma unroll
                for (int j = 0; j < 8; ++j)
                    acc[i][j] += xv[i] * wv[j];
        }
        __syncthreads();
    }

#pragma unroll
    for (int i = 0; i < 4; ++i) {
        const int gr = rowBase + ty * 4 + i;
        if (gr < N_NODES) {
            float4 o0 = {acc[i][0], acc[i][1], acc[i][2], acc[i][3]};
            float4 o1 = {acc[i][4], acc[i][5], acc[i][6], acc[i][7]};
            *(float4*)(Y + (size_t)gr * F + tx * 8) = o0;
            *(float4*)(Y + (size_t)gr * F + tx * 8 + 4) = o1;
        }
    }
}

// ---------------- CSR SpMM: half-wave per row, float4 gathers ----------------
// 32 lanes per row, each lane covers 4 columns (float4 = 16 B, coalescing
// sweet spot). One wave = 2 rows -> one vmem instruction covers 2 edges.
// Block 256 = 8 rows; grid = N_NODES/8 exact.
__global__ __launch_bounds__(256) void spmm_csr(const float* __restrict__ X,
                                                const int* __restrict__ row_ptr,
                                                const int* __restrict__ scol,
                                                const float* __restrict__ sw,
                                                float* __restrict__ Out, int relu_out) {
    const int tid  = threadIdx.x;
    const int lane = tid & 31;
    const int sub  = tid >> 5;                 // 0..7
    const int row  = blockIdx.x * 8 + sub;

    const int beg = row_ptr[row];
    const int end = row_ptr[row + 1];

    float4 a0 = {0.f, 0.f, 0.f, 0.f}, a1 = {0.f, 0.f, 0.f, 0.f};
    int i = beg;
    for (; i + 1 < end; i += 2) {
        const int   c0 = scol[i],   c1 = scol[i + 1];
        const float w0 = sw[i],     w1 = sw[i + 1];
        const float4 v0 = ((const float4*)(X + (size_t)c0 * F))[lane];
        const float4 v1 = ((const float4*)(X + (size_t)c1 * F))[lane];
        a0.x += w0 * v0.x; a0.y += w0 * v0.y; a0.z += w0 * v0.z; a0.w += w0 * v0.w;
        a1.x += w1 * v1.x; a1.y += w1 * v1.y; a1.z += w1 * v1.z; a1.w += w1 * v1.w;
    }
    if (i < end) {
        const int   c0 = scol[i];
        const float w0 = sw[i];
        const float4 v0 = ((const float4*)(X + (size_t)c0 * F))[lane];
        a0.x += w0 * v0.x; a0.y += w0 * v0.y; a0.z += w0 * v0.z; a0.w += w0 * v0.w;
    }
    float4 r;
    r.x = a0.x + a1.x; r.y = a0.y + a1.y;
    r.z = a0.z + a1.z; r.w = a0.w + a1.w;
    if (relu_out) {
        r.x = fmaxf(r.x, 0.0f); r.y = fmaxf(r.y, 0.0f);
        r.z = fmaxf(r.z, 0.0f); r.w = fmaxf(r.w, 0.0f);
    }
    ((float4*)(Out + (size_t)row * F))[lane] = r;
}

// ---------------- launch ----------------

extern "C" void kernel_launch(void* const* d_in, const int* in_sizes, int n_in,
                              void* d_out, int out_size, void* d_ws, size_t ws_size,
                              hipStream_t stream) {
    const float* x    = (const float*)d_in[0];
    const int*   erow = (const int*)d_in[1];
    const int*   ecol = (const int*)d_in[2];
    const float* ew   = (const float*)d_in[3];
    const float* w1   = (const float*)d_in[4];
    const float* w2   = (const float*)d_in[5];
    const float* w3   = (const float*)d_in[6];
    float* out = (float*)d_out;

    char* ws = (char*)d_ws;
    size_t off = 0;
    auto alloc = [&](size_t bytes) -> char* {
        char* p = ws + off;
        off += (bytes + 255) & ~(size_t)255;
        return p;
    };
    float* buf0    = (float*)alloc((size_t)N_NODES * F * sizeof(float)); // 51.2 MB
    int*   counts  = (int*)  alloc((size_t)N_NODES * sizeof(int));
    int*   row_ptr = (int*)  alloc(((size_t)N_NODES + 1) * sizeof(int));
    int*   scol    = (int*)  alloc((size_t)N_EDGES * sizeof(int));
    float* swgt    = (float*)alloc((size_t)N_EDGES * sizeof(float));
    int*   bsums   = (int*)  alloc((size_t)SCAN_NB * sizeof(int));
    int*   boffs   = (int*)  alloc((size_t)SCAN_NB * sizeof(int));

    // --- CSR build (once; reused by all 3 layers) ---
    hipMemsetAsync(counts, 0, (size_t)N_NODES * sizeof(int), stream);
    edge_histogram<<<N_EDGES / 256, 256, 0, stream>>>(erow, counts);
    scan_block_sums<<<SCAN_NB, SCAN_B, 0, stream>>>(counts, bsums);
    scan_bsums<<<1, 128, 0, stream>>>(bsums, boffs);
    scan_final<<<SCAN_NB, SCAN_B, 0, stream>>>(counts, boffs, row_ptr);
    hipMemsetAsync(counts, 0, (size_t)N_NODES * sizeof(int), stream);
    csr_fill<<<N_EDGES / 256, 256, 0, stream>>>(erow, ecol, ew, row_ptr, counts, scol, swgt);

    const int ggrid = (N_NODES + BM - 1) / BM;   // 1563
    const int sgrid = N_NODES / 8;               // 12500 exact

    // Layer 1
    gemm_tiled<<<ggrid, 256, 0, stream>>>(x, w1, buf0, 0);
    spmm_csr<<<sgrid, 256, 0, stream>>>(buf0, row_ptr, scol, swgt, out, 0);
    // Layer 2
    gemm_tiled<<<ggrid, 256, 0, stream>>>(out, w2, buf0, 1);
    spmm_csr<<<sgrid, 256, 0, stream>>>(buf0, row_ptr, scol, swgt, out, 0);
    // Layer 3
    gemm_tiled<<<ggrid, 256, 0, stream>>>(out, w3, buf0, 1);
    spmm_csr<<<sgrid, 256, 0, stream>>>(buf0, row_ptr, scol, swgt, out, 1);
}

// Round 5
// 527.493 us; speedup vs baseline: 16.6351x; 1.4550x over previous
//
#include <hip/hip_runtime.h>

#define N_NODES 100000
#define N_EDGES 1600000
#define F 128

#define SCAN_B 1024
#define SCAN_NB ((N_NODES + SCAN_B - 1) / SCAN_B)   // 98

typedef short bf16x8 __attribute__((ext_vector_type(8)));
typedef float f32x4  __attribute__((ext_vector_type(4)));

union ABFrag {
    bf16x8 v;
    unsigned short u[8];
    uint4  q;
};

__device__ __forceinline__ unsigned short f2bf(float f) {
    unsigned int u = __float_as_uint(f);
    u += 0x7fffu + ((u >> 16) & 1u);   // RNE
    return (unsigned short)(u >> 16);
}
__device__ __forceinline__ float bf2f(unsigned short s) {
    return __uint_as_float(((unsigned int)s) << 16);
}

// ---------------- CSR build ----------------

__global__ void edge_histogram(const int* __restrict__ erow, int* __restrict__ counts) {
    const int e = blockIdx.x * blockDim.x + threadIdx.x;
    atomicAdd(&counts[erow[e]], 1);
}

__global__ void scan_block_sums(const int* __restrict__ counts, int* __restrict__ bsums) {
    __shared__ int s[SCAN_B];
    const int t = threadIdx.x;
    const int idx = blockIdx.x * SCAN_B + t;
    int v = (idx < N_NODES) ? counts[idx] : 0;
    s[t] = v;
    __syncthreads();
    for (int off = SCAN_B / 2; off > 0; off >>= 1) {
        if (t < off) s[t] += s[t + off];
        __syncthreads();
    }
    if (t == 0) bsums[blockIdx.x] = s[0];
}

__global__ void scan_bsums(const int* __restrict__ bsums, int* __restrict__ boffs) {
    __shared__ int s[128];
    const int t = threadIdx.x;
    int v = (t < SCAN_NB) ? bsums[t] : 0;
    s[t] = v;
    __syncthreads();
    for (int off = 1; off < 128; off <<= 1) {
        int u = (t >= off) ? s[t - off] : 0;
        __syncthreads();
        s[t] += u;
        __syncthreads();
    }
    if (t < SCAN_NB) boffs[t] = s[t] - v;
}

__global__ void scan_final(const int* __restrict__ counts, const int* __restrict__ boffs,
                           int* __restrict__ row_ptr) {
    __shared__ int s[SCAN_B];
    const int t = threadIdx.x;
    const int idx = blockIdx.x * SCAN_B + t;
    int v = (idx < N_NODES) ? counts[idx] : 0;
    s[t] = v;
    __syncthreads();
    for (int off = 1; off < SCAN_B; off <<= 1) {
        int u = (t >= off) ? s[t - off] : 0;
        __syncthreads();
        s[t] += u;
        __syncthreads();
    }
    if (idx < N_NODES) row_ptr[idx] = boffs[blockIdx.x] + s[t] - v;
    if (idx == 0) row_ptr[N_NODES] = N_EDGES;
}

// One 8 B paired store per edge: {col, weight-bits}.
__global__ void csr_fill(const int* __restrict__ erow, const int* __restrict__ ecol,
                         const float* __restrict__ ewgt,
                         const int* __restrict__ row_ptr, int* __restrict__ cursor,
                         int2* __restrict__ pairs) {
    const int e = blockIdx.x * blockDim.x + threadIdx.x;
    const int dst = erow[e];
    const int pos = atomicAdd(&cursor[dst], 1);
    int2 p;
    p.x = ecol[e];
    p.y = __float_as_int(ewgt[e]);
    pairs[row_ptr[dst] + pos] = p;
}

// ---------------- W^T -> bf16 (once per weight) ----------------
__global__ void transpose_w_bf16(const float* __restrict__ W, unsigned short* __restrict__ Wt) {
    const int i = blockIdx.x * 256 + threadIdx.x;   // 0..16383
    const int n = i >> 7;
    const int k = i & 127;
    Wt[i] = f2bf(W[k * F + n]);                     // Wt[n][k] = W[k][n]
}

// ---------------- MFMA bf16 GEMM ----------------
// Block 256 = 4 waves; block computes 64 rows x 128 cols. Wave w owns rows
// [blk*64 + w*16, +16). K = 4 k-tiles of 32. W^T staged in LDS in frag order
// (slot = (kt*8+nt)*64 + lane, 8 shorts each) -> conflict-free ds_read_b128.
// A-frag loaded straight from global: lane reads 16 B (8 bf16) of its row.
// Verified layouts: A[m=lane&15][k=(lane>>4)*8+j]; B from W^T row n=lane&15;
// D[row=(lane>>4)*4+r][col=lane&15].
__global__ __launch_bounds__(256) void gemm_mfma(
    const float* __restrict__ Xf,            // fp32 input (layer 1) or null
    const unsigned short* __restrict__ Xb,   // bf16 input (layers 2/3) or null
    const unsigned short* __restrict__ Wt,   // bf16 W^T [128][128]
    unsigned short* __restrict__ Y,          // bf16 out [N][128]
    int use_f32_in)                          // 1: Xf no relu; 0: Xb with relu
{
    __shared__ unsigned short Wl[4 * 8 * 64 * 8];   // 32 KB

    const int tid  = threadIdx.x;
    const int wave = tid >> 6;
    const int lane = tid & 63;

    // Stage W^T in frag order.
    for (int s = tid; s < 2048; s += 256) {
        const int ln  = s & 63;
        const int ntk = s >> 6;           // kt*8 + nt
        const int nt  = ntk & 7;
        const int kt  = ntk >> 3;
        const int n   = nt * 16 + (ln & 15);
        const int k   = kt * 32 + (ln >> 4) * 8;
        *(uint4*)(&Wl[s * 8]) = *(const uint4*)(Wt + n * F + k);
    }
    __syncthreads();

    const int m     = blockIdx.x * 64 + wave * 16 + (lane & 15);
    const bool mval = (m < N_NODES);
    const int kq    = (lane >> 4) * 8;

    f32x4 acc[8] = {};

#pragma unroll
    for (int kt = 0; kt < 4; ++kt) {
        ABFrag a;
        if (mval) {
            if (use_f32_in) {
                const float* p = Xf + (size_t)m * F + kt * 32 + kq;
                const float4 u0 = *(const float4*)p;
                const float4 u1 = *(const float4*)(p + 4);
                a.u[0] = f2bf(u0.x); a.u[1] = f2bf(u0.y);
                a.u[2] = f2bf(u0.z); a.u[3] = f2bf(u0.w);
                a.u[4] = f2bf(u1.x); a.u[5] = f2bf(u1.y);
                a.u[6] = f2bf(u1.z); a.u[7] = f2bf(u1.w);
            } else {
                a.q = *(const uint4*)(Xb + (size_t)m * F + kt * 32 + kq);
#pragma unroll
                for (int j = 0; j < 8; ++j)
                    if (a.u[j] & 0x8000u) a.u[j] = 0;   // relu on bf16 bits
            }
        } else {
            a.q = make_uint4(0, 0, 0, 0);
        }
#pragma unroll
        for (int nt = 0; nt < 8; ++nt) {
            ABFrag b;
            b.q = *(const uint4*)(&Wl[((kt * 8 + nt) * 64 + lane) * 8]);
            acc[nt] = __builtin_amdgcn_mfma_f32_16x16x32_bf16(a.v, b.v, acc[nt], 0, 0, 0);
        }
    }

    const int rbase = blockIdx.x * 64 + wave * 16 + (lane >> 4) * 4;
    const int cbase = lane & 15;
#pragma unroll
    for (int r = 0; r < 4; ++r) {
        const int row = rbase + r;
        if (row < N_NODES) {
#pragma unroll
            for (int nt = 0; nt < 8; ++nt) {
                Y[(size_t)row * F + nt * 16 + cbase] = f2bf(acc[nt][r]);
            }
        }
    }
}

// ---------------- CSR SpMM, bf16 gather ----------------
// 32 lanes per row, lane covers 4 columns (8 B bf16 load -> 256 B per edge).
// mode 0: store bf16 raw; mode 1: store fp32 relu (final layer).
__global__ __launch_bounds__(256) void spmm_csr_bf16(
    const unsigned short* __restrict__ Xb,
    const int* __restrict__ row_ptr,
    const int2* __restrict__ pairs,
    unsigned short* __restrict__ Ob,
    float* __restrict__ Of,
    int mode) {
    const int tid  = threadIdx.x;
    const int lane = tid & 31;
    const int sub  = tid >> 5;
    const int row  = blockIdx.x * 8 + sub;

    const int beg = row_ptr[row];
    const int end = row_ptr[row + 1];

    float4 a0 = {0.f, 0.f, 0.f, 0.f}, a1 = {0.f, 0.f, 0.f, 0.f};
    int i = beg;
    for (; i + 1 < end; i += 2) {
        const int2 p0 = pairs[i];
        const int2 p1 = pairs[i + 1];
        const ushort4 v0 = ((const ushort4*)(Xb + (size_t)p0.x * F))[lane];
        const ushort4 v1 = ((const ushort4*)(Xb + (size_t)p1.x * F))[lane];
        const float w0 = __int_as_float(p0.y);
        const float w1 = __int_as_float(p1.y);
        a0.x += w0 * bf2f(v0.x); a0.y += w0 * bf2f(v0.y);
        a0.z += w0 * bf2f(v0.z); a0.w += w0 * bf2f(v0.w);
        a1.x += w1 * bf2f(v1.x); a1.y += w1 * bf2f(v1.y);
        a1.z += w1 * bf2f(v1.z); a1.w += w1 * bf2f(v1.w);
    }
    if (i < end) {
        const int2 p0 = pairs[i];
        const ushort4 v0 = ((const ushort4*)(Xb + (size_t)p0.x * F))[lane];
        const float w0 = __int_as_float(p0.y);
        a0.x += w0 * bf2f(v0.x); a0.y += w0 * bf2f(v0.y);
        a0.z += w0 * bf2f(v0.z); a0.w += w0 * bf2f(v0.w);
    }
    float4 r;
    r.x = a0.x + a1.x; r.y = a0.y + a1.y;
    r.z = a0.z + a1.z; r.w = a0.w + a1.w;
    if (mode) {
        r.x = fmaxf(r.x, 0.f); r.y = fmaxf(r.y, 0.f);
        r.z = fmaxf(r.z, 0.f); r.w = fmaxf(r.w, 0.f);
        ((float4*)(Of + (size_t)row * F))[lane] = r;
    } else {
        ushort4 o;
        o.x = f2bf(r.x); o.y = f2bf(r.y); o.z = f2bf(r.z); o.w = f2bf(r.w);
        ((ushort4*)(Ob + (size_t)row * F))[lane] = o;
    }
}

// ---------------- launch ----------------

extern "C" void kernel_launch(void* const* d_in, const int* in_sizes, int n_in,
                              void* d_out, int out_size, void* d_ws, size_t ws_size,
                              hipStream_t stream) {
    const float* x    = (const float*)d_in[0];
    const int*   erow = (const int*)d_in[1];
    const int*   ecol = (const int*)d_in[2];
    const float* ew   = (const float*)d_in[3];
    const float* w1   = (const float*)d_in[4];
    const float* w2   = (const float*)d_in[5];
    const float* w3   = (const float*)d_in[6];
    float* out = (float*)d_out;

    char* ws = (char*)d_ws;
    size_t off = 0;
    auto alloc = [&](size_t bytes) -> char* {
        char* p = ws + off;
        off += (bytes + 255) & ~(size_t)255;
        return p;
    };
    unsigned short* bufA = (unsigned short*)alloc((size_t)N_NODES * F * 2); // 25.6 MB
    unsigned short* bufB = (unsigned short*)alloc((size_t)N_NODES * F * 2); // 25.6 MB
    int2*  pairs   = (int2*)alloc((size_t)N_EDGES * sizeof(int2));          // 12.8 MB
    int*   counts  = (int*) alloc((size_t)N_NODES * sizeof(int));
    int*   row_ptr = (int*) alloc(((size_t)N_NODES + 1) * sizeof(int));
    int*   bsums   = (int*) alloc((size_t)SCAN_NB * sizeof(int));
    int*   boffs   = (int*) alloc((size_t)SCAN_NB * sizeof(int));
    unsigned short* wt1 = (unsigned short*)alloc((size_t)F * F * 2);
    unsigned short* wt2 = (unsigned short*)alloc((size_t)F * F * 2);
    unsigned short* wt3 = (unsigned short*)alloc((size_t)F * F * 2);

    // --- CSR build (once; reused by all 3 layers) ---
    hipMemsetAsync(counts, 0, (size_t)N_NODES * sizeof(int), stream);
    edge_histogram<<<N_EDGES / 256, 256, 0, stream>>>(erow, counts);
    scan_block_sums<<<SCAN_NB, SCAN_B, 0, stream>>>(counts, bsums);
    scan_bsums<<<1, 128, 0, stream>>>(bsums, boffs);
    scan_final<<<SCAN_NB, SCAN_B, 0, stream>>>(counts, boffs, row_ptr);
    hipMemsetAsync(counts, 0, (size_t)N_NODES * sizeof(int), stream);
    csr_fill<<<N_EDGES / 256, 256, 0, stream>>>(erow, ecol, ew, row_ptr, counts, pairs);

    // --- Weight transposes to bf16 ---
    transpose_w_bf16<<<64, 256, 0, stream>>>(w1, wt1);
    transpose_w_bf16<<<64, 256, 0, stream>>>(w2, wt2);
    transpose_w_bf16<<<64, 256, 0, stream>>>(w3, wt3);

    const int ggrid = (N_NODES + 63) / 64;   // 1563
    const int sgrid = N_NODES / 8;           // 12500 exact

    // Layer 1
    gemm_mfma<<<ggrid, 256, 0, stream>>>(x, nullptr, wt1, bufA, 1);
    spmm_csr_bf16<<<sgrid, 256, 0, stream>>>(bufA, row_ptr, pairs, bufB, nullptr, 0);
    // Layer 2
    gemm_mfma<<<ggrid, 256, 0, stream>>>(nullptr, bufB, wt2, bufA, 0);
    spmm_csr_bf16<<<sgrid, 256, 0, stream>>>(bufA, row_ptr, pairs, bufB, nullptr, 0);
    // Layer 3
    gemm_mfma<<<ggrid, 256, 0, stream>>>(nullptr, bufB, wt3, bufA, 0);
    spmm_csr_bf16<<<sgrid, 256, 0, stream>>>(bufA, row_ptr, pairs, nullptr, out, 1);
}